// Round 6
// baseline (458.573 us; speedup 1.0000x reference)
//
#include <hip/hip_runtime.h>
#include <math.h>

// Problem constants (setup_inputs: block_size=2048, embedding_dim=256)
#define PB 2048
#define PD 256
// K = D/2 - 1 = 127 reference iterations. Nonzero pattern of plane p:
//   row 2i (i=0..126): col 2i -> cos(p*th_i), col 2i+2 -> -sin(p*th_i)
//   row 2i+2:          col 2i -> sin(p*th_i)
//   final diag (254,254) -> cos(p*th_126); odd rows/cols all zero.
//
// Session ledger:
//   R0/R2/R3 fused one-pass fills: stores cap ~2.9-3.3 TB/s (suspect L2
//     write-allocate fetch doubling traffic) -> abandoned.
//   R1/R4/R5: hipMemsetAsync (runtime fill path, 6.3 TB/s measured) + sparse
//     band fixup. R5 (self-contained band, 2 dispatches) = 453 us total,
//     our portion ~115 us vs ~100-110 floor.
// This round: line-granular store predication (only the 128B L2 lines that
// actually contain a nonzero col get written; 114/128 rows need just one
// line -> band traffic 64 -> ~35.5 MiB) + nontemporal full-line stores to
// dodge any write-allocate fetch.

// theta_i = 10000^(-2*(i-1)/D)  [the (i-1) quirk is intentional, per reference]
//         = exp2( -(i-1) * 2*log2(10000)/256 )
__device__ __forceinline__ float theta_of(int i) {
    const float c = 0.10381025187f; // 2*log2(10000)/256
    return exp2f(-(float)(i - 1) * c);
}

// One block per plane p; wave w (of 4) handles even rows r=2j, j in
// [32w, 32w+32). Lane l computes sincos(p * th_{clamp(32w-1+l)}) so lane t
// holds th_{j-1} for j = 32w+t and lane t+1 holds th_j. Per row the wave
// stores only the needed 128B line(s) of a 256B-aligned window covering
// cols {r-2, r, r+2}; all other bytes stay memset-zero.
__global__ __launch_bounds__(256) void rope_band3_kernel(float* __restrict__ out) {
    int p    = (int)blockIdx.x;          // 0..2047
    int w    = (int)(threadIdx.x >> 6);  // 0..3
    int lane = (int)(threadIdx.x & 63u);

    int i = 32 * w - 1 + lane;           // value index this lane computes
    i = (i < 0) ? 0 : (i > 127 ? 127 : i);
    float s, c;
    __builtin_sincosf((float)p * theta_of(i), &s, &c);

    float* plane = out + (unsigned int)p * 65536u;

    #pragma unroll
    for (int t = 0; t < 32; ++t) {
        int j = 32 * w + t;              // 0..127
        int r = 2 * j;                   // even row 0..254
        // broadcasts: lane indices are compile-time constants (unrolled)
        float ssub = __shfl(s, t, 64);        // sin(p*th_{j-1})   (valid j>=1)
        float ssup = __shfl(s, t + 1, 64);    // sin(p*th_j)
        float cj   = __shfl(c, t + 1, 64);    // cos(p*th_j)
        float cjm1 = __shfl(c, t, 64);        // cos(p*th_{j-1})
        float cv   = (j == 127) ? cjm1 : cj;  // cos(p*th_min(j,126))

        // 64-col (256B) window, 128B-aligned, containing cols r-2..r+2.
        int base = (r >= 2) ? ((r - 2) & ~31) : 0;
        if (base > 192) base = 192;
        int col = base + lane;

        // 128B line of this lane: [lo, lo+31]. Store only if the line holds
        // one of the (existing) nonzero cols; unstored lines keep memset 0s.
        int lo = base + ((lane >> 5) << 5);
        int hi = lo + 31;
        bool needed = (r >= lo && r <= hi)
                   || (r >= 2   && r - 2 >= lo && r - 2 <= hi)
                   || (r <= 252 && r + 2 >= lo && r + 2 <= hi);

        // col==r-2 unreachable for r==0; col==r+2 unreachable for r==254
        // (max col 255): value guards are implicit.
        float val = (col == r) ? cv
                  : (col == r - 2) ? ssub
                  : (col == r + 2) ? -ssup
                  : 0.0f;

        if (needed)
            __builtin_nontemporal_store(val,
                &plane[(unsigned int)r * 256u + (unsigned int)col]);
    }
}

extern "C" void kernel_launch(void* const* d_in, const int* in_sizes, int n_in,
                              void* d_out, int out_size, void* d_ws, size_t ws_size,
                              hipStream_t stream) {
    (void)d_in; (void)in_sizes; (void)n_in; (void)d_ws; (void)ws_size;
    // 1) Zero the 512 MiB output on the runtime fill path (~6.3 TB/s).
    hipMemsetAsync(d_out, 0, (size_t)out_size, stream);
    // 2) Band fixup: 2048 blocks (one per plane) x 256 threads; ~35.5 MiB of
    //    full-line nontemporal stores.
    rope_band3_kernel<<<PB, 256, 0, stream>>>((float*)d_out);
}

// Round 7
// 454.038 us; speedup vs baseline: 1.0100x; 1.0100x over previous
//
#include <hip/hip_runtime.h>
#include <math.h>

// Problem constants (setup_inputs: block_size=2048, embedding_dim=256)
#define PB 2048
#define PD 256
// K = D/2 - 1 = 127 reference iterations. Nonzero pattern of plane p:
//   row 2i (i=0..126): col 2i -> cos(p*th_i), col 2i+2 -> -sin(p*th_i)
//   row 2i+2:          col 2i -> sin(p*th_i)
//   final diag (254,254) -> cos(p*th_126); odd rows/cols all zero.
//
// FINAL (session-best, round 5 = 453 us). Ledger:
//   R0/R2/R3 fused one-pass fills: stores cap ~2.9-3.3 TB/s regardless of
//     trig/divergence/store-flavor/grid -> abandoned.
//   R1/R4: memset + fixup variants, ~470 us.
//   R5 (this): memset + self-contained band kernel, 2 dispatches, 453 us.
//   R6: line-predicated nt stores: 458.6 us (regression; band is latency-
//     not store-bound) -> reverted per pre-commit.
// Floor analysis: total = poison fill ~340 (harness, untouchable) + memset
// 512MiB @6.3TB/s ~85 + band ~15-25 incl. launch gap. Roofline.

// theta_i = 10000^(-2*(i-1)/D)  [the (i-1) quirk is intentional, per reference]
//         = exp2( -(i-1) * 2*log2(10000)/256 )
__device__ __forceinline__ float theta_of(int i) {
    const float c = 0.10381025187f; // 2*log2(10000)/256
    return exp2f(-(float)(i - 1) * c);
}

// One block per plane p; wave w (of 4) handles even rows r=2j, j in
// [32w, 32w+32). Lane l computes sincos(p * th_{clamp(32w-1+l)}) so that
// within the wave, lane t   holds th_{j-1} for j = 32w+t   (ssub),
//                  lane t+1 holds th_j                      (ssup, cos).
// Each row stores one 256B-aligned 64-float window covering cols
// {r-2, r, r+2} (full-line coalesced, no RMW); memset provides the rest.
__global__ __launch_bounds__(256) void rope_band2_kernel(float* __restrict__ out) {
    int p    = (int)blockIdx.x;          // 0..2047
    int w    = (int)(threadIdx.x >> 6);  // 0..3
    int lane = (int)(threadIdx.x & 63u);

    int i = 32 * w - 1 + lane;           // value index this lane computes
    i = (i < 0) ? 0 : (i > 127 ? 127 : i);
    float s, c;
    __builtin_sincosf((float)p * theta_of(i), &s, &c);

    float* plane = out + (unsigned int)p * 65536u;

    #pragma unroll
    for (int t = 0; t < 32; ++t) {
        int j = 32 * w + t;              // 0..127
        int r = 2 * j;                   // even row 0..254
        // broadcasts: lane indices are compile-time constants (unrolled)
        float ssub = __shfl(s, t, 64);        // sin(p*th_{j-1}) (j>=1)
        float ssup = __shfl(s, t + 1, 64);    // sin(p*th_j)
        float cj   = __shfl(c, t + 1, 64);    // cos(p*th_j)
        float cjm1 = __shfl(c, t, 64);        // cos(p*th_{j-1})
        float cv   = (j == 127) ? cjm1 : cj;  // cos(p*th_min(j,126)); uniform sel

        // 64-col window, 128B-aligned, containing cols r-2..r+2, inside row.
        int base = (r >= 2) ? ((r - 2) & ~31) : 0;
        if (base > 192) base = 192;
        int col = base + lane;

        // col==r-2 unreachable for r==0 (would be -2); col==r+2 unreachable
        // for r==254 (max col 255): guards are implicit.
        float val = (col == r) ? cv
                  : (col == r - 2) ? ssub
                  : (col == r + 2) ? -ssup
                  : 0.0f;

        plane[(unsigned int)r * 256u + (unsigned int)col] = val;
    }
}

extern "C" void kernel_launch(void* const* d_in, const int* in_sizes, int n_in,
                              void* d_out, int out_size, void* d_ws, size_t ws_size,
                              hipStream_t stream) {
    (void)d_in; (void)in_sizes; (void)n_in; (void)d_ws; (void)ws_size;
    // 1) Zero the 512 MiB output on the runtime fill path (~6.3 TB/s).
    hipMemsetAsync(d_out, 0, (size_t)out_size, stream);
    // 2) Scatter the band: 2048 blocks (one per plane) x 256 threads;
    //    8 blocks/CU, 64 MiB of full-line coalesced stores.
    rope_band2_kernel<<<PB, 256, 0, stream>>>((float*)d_out);
}